// Round 1
// baseline (295150.049 us; speedup 1.0000x reference)
//
#include <hip/hip_runtime.h>
#include <stdint.h>

// ---------------- problem dims ----------------
#define T_FRAMES 8192
#define DIM_D 512
#define DIM_J 640
#define DIM_E 512
#define DIM_H 640
#define DIM_V 4096
#define G4H   2560
#define TOK_BLANK 4095
#define NBLK 256
#define NTHR 256

// ---------------- workspace layout (float offsets) ----------------
#define WF_X      0          // x = tanh(enc+dp) [640]
#define WF_H2     640        // raw new hidden  [640]
#define WF_HB0    1280       // committed h, parity 0 [640]
#define WF_HB1    1920       // committed h, parity 1 [640]
#define WF_CB     2560       // committed c [640]
#define WF_DPC    3200       // committed dp [640]
#define WF_STATS  3840       // per-block {max,sumexp,argmax_bits,pad} [256*4]
#define WF_END    4864
// flags (u32), each padded to 16 u32 (64B line)
#define FLG_BAR   0
#define FLG_STAT  (256*16)
#define FLG_CNT   (512*16)

__device__ __forceinline__ float sigm(float x) { return 1.f / (1.f + __expf(-x)); }

__device__ __forceinline__ void st_rel(unsigned* p, unsigned v) {
  __hip_atomic_store(p, v, __ATOMIC_RELEASE, __HIP_MEMORY_SCOPE_AGENT);
}
__device__ __forceinline__ unsigned ld_rlx(const unsigned* p) {
  return __hip_atomic_load(p, __ATOMIC_RELAXED, __HIP_MEMORY_SCOPE_AGENT);
}

// all-poll-all grid barrier: block writes its flag=seq (release), every thread
// polls one block's flag, acquire-fence, syncthreads.  seq strictly increases
// per use; 0xAAAAAAAA poison is negative under (int)(f-seq) so it never
// falsely releases.
__device__ __forceinline__ void gbar(unsigned* flags, int bid, int tid, unsigned seq) {
  __syncthreads();
  if (tid == 0) st_rel(&flags[bid * 16], seq);
  unsigned f;
  do { f = ld_rlx(&flags[tid * 16]); } while ((int)(f - seq) < 0);
  __builtin_amdgcn_fence(__ATOMIC_ACQUIRE, "agent");
  __syncthreads();
}

extern "C" __global__ void __launch_bounds__(NTHR, 1)
rnnt_greedy_kernel(const float* __restrict__ enc,
                   const float* __restrict__ embed,
                   const float* __restrict__ Wx,
                   const float* __restrict__ Wh,
                   const float* __restrict__ b_lstm,
                   const float* __restrict__ Wdp,
                   const float* __restrict__ bdp,
                   const float* __restrict__ Wenc,
                   const float* __restrict__ benc,
                   const float* __restrict__ Wout,
                   const float* __restrict__ bout,
                   float* __restrict__ out,
                   float* __restrict__ wsf,
                   unsigned* __restrict__ wsflags,
                   unsigned long long* __restrict__ wsgo)
{
  __shared__ float smem[28544];   // 114,176 B static LDS -> 1 block/CU

  const int tid  = threadIdx.x;
  const int bid  = blockIdx.x;
  const int wid  = tid >> 6;
  const int lane = tid & 63;

  float* woutl   = smem;           // 16*640   Wout column slice, [v][j]
  float* wxhl    = smem + 10240;   // 12*1152  [gatecol][k] (k<512:Wx, else Wh)
  float* wdpl    = smem + 24064;   // 3*640    Wdp column slice, [j][k]
  float* x_lds   = smem + 25984;   // 640
  float* ehbuf   = smem + 26624;   // 1152 (e | h)
  float* h2l     = smem + 27776;   // 640
  float* logit_l = smem + 28416;   // 16
  float* g_l     = smem + 28432;   // 12
  float* bout_l  = smem + 28444;   // 16
  float* blst_l  = smem + 28460;   // 12
  float* bdp_l   = smem + 28472;   // 4
  float* red     = smem + 28476;   // 24 scratch for reduces/broadcast
  float* enc_lds = smem;           // init-time overlay: 32*512

  float* xg     = wsf + WF_X;
  float* h2g    = wsf + WF_H2;
  float* hb0    = wsf + WF_HB0;
  float* hb1    = wsf + WF_HB1;
  float* cbg    = wsf + WF_CB;
  float* dpcg   = wsf + WF_DPC;
  float* statsg = wsf + WF_STATS;
  unsigned* barflag = wsflags + FLG_BAR;
  unsigned* sflag   = wsflags + FLG_STAT;
  unsigned long long* goTok = wsgo;
  unsigned long long* goLse = wsgo + 1;

  const int h0 = (bid * 5) >> 1;          // bid*640/256  (owned h == owned j)
  const int h1 = ((bid + 1) * 5) >> 1;
  const int nH = h1 - h0;                 // 2 or 3
  const int ncols = nH * 4;
  const int vb = bid << 4;                // 16 vocab entries per block

  // ================= init: enc_proj -> out[t][0:640] =================
  {
    const int r0 = bid * 32;
    const float4* src = (const float4*)(enc + (size_t)r0 * DIM_D);
    float4* dst = (float4*)enc_lds;
    for (int i = tid; i < 32 * DIM_D / 4; i += NTHR) dst[i] = src[i];
    __syncthreads();
    for (int jj = tid; jj < DIM_J; jj += NTHR) {
      float acc[32];
      #pragma unroll
      for (int r = 0; r < 32; ++r) acc[r] = 0.f;
      for (int k = 0; k < DIM_D; ++k) {
        float w = Wenc[(size_t)k * DIM_J + jj];
        #pragma unroll
        for (int r = 0; r < 32; ++r) acc[r] += enc_lds[r * DIM_D + k] * w;
      }
      float bj = benc[jj];
      for (int r = 0; r < 32; ++r) out[(size_t)(r0 + r) * DIM_V + jj] = acc[r] + bj;
    }
    __syncthreads();
  }

  // ================= init: weight slices -> LDS =================
  for (int idx = tid; idx < 16 * DIM_J; idx += NTHR) {
    int j = idx >> 4, vl = idx & 15;
    woutl[vl * DIM_J + j] = Wout[(size_t)j * DIM_V + vb + vl];
  }
  for (int idx = tid; idx < ncols * 1152; idx += NTHR) {
    int c = idx / 1152, k = idx - c * 1152;
    int hl = c >> 2, gate = c & 3;
    int gcol = gate * DIM_H + h0 + hl;
    wxhl[c * 1152 + k] = (k < DIM_E) ? Wx[(size_t)k * G4H + gcol]
                                     : Wh[(size_t)(k - DIM_E) * G4H + gcol];
  }
  for (int idx = tid; idx < nH * DIM_H; idx += NTHR) {
    int jl = idx / DIM_H, k = idx - jl * DIM_H;
    wdpl[jl * DIM_H + k] = Wdp[(size_t)k * DIM_J + h0 + jl];
  }
  if (tid < 16) bout_l[tid] = bout[vb + tid];
  if (tid < ncols) { int hl = tid >> 2, gate = tid & 3; blst_l[tid] = b_lstm[gate * DIM_H + h0 + hl]; }
  if (tid < nH) bdp_l[tid] = bdp[h0 + tid];

  unsigned bs = 1;
  gbar(barflag, bid, tid, bs); ++bs;   // enc_proj + all LDS ready

  // ================= priming: pred_step(BLANK, h=0, c=0) =================
  {
    for (int i = tid; i < DIM_E; i += NTHR) ehbuf[i] = embed[(size_t)TOK_BLANK * DIM_E + i];
    for (int i = tid; i < DIM_H; i += NTHR) ehbuf[DIM_E + i] = 0.f;
    __syncthreads();
    for (int c = wid; c < ncols; c += 4) {
      const float* wp = wxhl + c * 1152;
      float acc = 0.f;
      #pragma unroll
      for (int i = 0; i < 18; ++i) { int k = lane + (i << 6); acc += ehbuf[k] * wp[k]; }
      #pragma unroll
      for (int m = 32; m; m >>= 1) acc += __shfl_xor(acc, m);
      if (lane == 0) g_l[c] = acc + blst_l[c];
    }
    __syncthreads();
    if (tid < nH) {
      int gh = h0 + tid;
      float gi = g_l[tid * 4 + 0], gf = g_l[tid * 4 + 1];
      float gg = g_l[tid * 4 + 2], go_ = g_l[tid * 4 + 3];
      (void)gf;  // c_old = 0
      float c2 = sigm(gi) * tanhf(gg);
      float h2v = sigm(go_) * tanhf(c2);
      h2g[gh] = h2v;
      hb0[gh] = h2v;     // committed unconditionally
      cbg[gh] = c2;
    }
    gbar(barflag, bid, tid, bs); ++bs;
    // dp0 and x for enc row 0
    for (int i = tid; i < DIM_H; i += NTHR) h2l[i] = h2g[i];
    __syncthreads();
    if (wid < nH) {
      const float* wp = wdpl + wid * DIM_H;
      float acc = 0.f;
      #pragma unroll
      for (int i = 0; i < 10; ++i) { int k = lane + (i << 6); acc += h2l[k] * wp[k]; }
      #pragma unroll
      for (int m = 32; m; m >>= 1) acc += __shfl_xor(acc, m);
      if (lane == 0) {
        int gj = h0 + wid;
        float dp0 = acc + bdp_l[wid];
        dpcg[gj] = dp0;
        xg[gj] = tanhf(out[gj] + dp0);   // enc_proj[0][gj]
      }
    }
    gbar(barflag, bid, tid, bs); ++bs;
  }

  // ================= main sequential decode =================
  for (int t = 0; t < T_FRAMES; ++t) {
    const unsigned seqt = (unsigned)(t + 1);

    // ---- phase 1: logits slice + block stats ----
    for (int i = tid; i < DIM_J; i += NTHR) x_lds[i] = xg[i];
    __syncthreads();
    {
      const float* w0 = woutl + (wid * 4 + 0) * DIM_J;
      const float* w1 = woutl + (wid * 4 + 1) * DIM_J;
      const float* w2 = woutl + (wid * 4 + 2) * DIM_J;
      const float* w3 = woutl + (wid * 4 + 3) * DIM_J;
      float a0 = 0, a1 = 0, a2 = 0, a3 = 0;
      #pragma unroll
      for (int i = 0; i < 10; ++i) {
        int k = lane + (i << 6);
        float xv = x_lds[k];
        a0 += xv * w0[k]; a1 += xv * w1[k]; a2 += xv * w2[k]; a3 += xv * w3[k];
      }
      #pragma unroll
      for (int m = 32; m; m >>= 1) {
        a0 += __shfl_xor(a0, m); a1 += __shfl_xor(a1, m);
        a2 += __shfl_xor(a2, m); a3 += __shfl_xor(a3, m);
      }
      if (lane == 0) {
        logit_l[wid * 4 + 0] = a0 + bout_l[wid * 4 + 0];
        logit_l[wid * 4 + 1] = a1 + bout_l[wid * 4 + 1];
        logit_l[wid * 4 + 2] = a2 + bout_l[wid * 4 + 2];
        logit_l[wid * 4 + 3] = a3 + bout_l[wid * 4 + 3];
      }
    }
    __syncthreads();
    if (wid == 0) {
      float v  = (lane < 16) ? logit_l[lane] : -3.4e38f;
      int   vi = vb + (lane & 15);
      float m = v; int mi = vi;
      #pragma unroll
      for (int s = 32; s; s >>= 1) {
        float om = __shfl_xor(m, s); int oi = __shfl_xor(mi, s);
        if (om > m || (om == m && oi < mi)) { m = om; mi = oi; }
      }
      float e = (lane < 16) ? __expf(v - m) : 0.f;
      #pragma unroll
      for (int s = 32; s; s >>= 1) e += __shfl_xor(e, s);
      if (lane == 0) {
        float4 st = make_float4(m, e, __int_as_float(mi), 0.f);
        *(float4*)(statsg + bid * 4) = st;
        st_rel(&sflag[bid * 16], seqt);
      }
    }

    // ---- block 0: combine stats -> tok, lse; publish go-words ----
    if (bid == 0) {
      unsigned f;
      do { f = ld_rlx(&sflag[tid * 16]); } while ((int)(f - seqt) < 0);
      __builtin_amdgcn_fence(__ATOMIC_ACQUIRE, "agent");
      float4 st = *(const float4*)(statsg + tid * 4);
      float wm = st.x; int wmi = __float_as_int(st.z);
      #pragma unroll
      for (int s = 32; s; s >>= 1) {
        float om = __shfl_xor(wm, s); int oi = __shfl_xor(wmi, s);
        if (om > wm || (om == wm && oi < wmi)) { wm = om; wmi = oi; }
      }
      if (lane == 0) { red[wid] = wm; ((int*)red)[4 + wid] = wmi; }
      __syncthreads();
      if (tid == 0) {
        float gm = red[0]; int gi_ = ((int*)red)[4];
        #pragma unroll
        for (int w = 1; w < 4; ++w) {
          float om = red[w]; int oi = ((int*)red)[4 + w];
          if (om > gm || (om == gm && oi < gi_)) { gm = om; gi_ = oi; }
        }
        red[8] = gm; ((int*)red)[9] = gi_;
      }
      __syncthreads();
      float gm = red[8]; int gtok = ((int*)red)[9];
      float term = st.y * __expf(st.x - gm);
      #pragma unroll
      for (int s = 32; s; s >>= 1) term += __shfl_xor(term, s);
      if (lane == 0) red[10 + wid] = term;
      __syncthreads();
      if (tid == 0) {
        float gs = red[10] + red[11] + red[12] + red[13];
        float lse = gm + __logf(gs);
        __hip_atomic_store(goTok, ((unsigned long long)seqt << 32) | (unsigned)gtok,
                           __ATOMIC_RELEASE, __HIP_MEMORY_SCOPE_AGENT);
        __hip_atomic_store(goLse, ((unsigned long long)seqt << 32) | (unsigned long long)__float_as_uint(lse),
                           __ATOMIC_RELEASE, __HIP_MEMORY_SCOPE_AGENT);
      }
    }

    // ---- all blocks: receive tok/lse ----
    if (tid == 0) {
      unsigned long long g;
      do { g = __hip_atomic_load(goTok, __ATOMIC_RELAXED, __HIP_MEMORY_SCOPE_AGENT); }
      while ((unsigned)(g >> 32) != seqt);
      ((int*)red)[14] = (int)(g & 0xffffffffu);
      do { g = __hip_atomic_load(goLse, __ATOMIC_RELAXED, __HIP_MEMORY_SCOPE_AGENT); }
      while ((unsigned)(g >> 32) != seqt);
      red[15] = __uint_as_float((unsigned)(g & 0xffffffffu));
    }
    __syncthreads();
    const int tok = ((int*)red)[14];
    const float lse = red[15];
    const bool nb = (tok != TOK_BLANK);

    // ---- phase 2: logp write + LSTM slice + commit h/c ----
    if (tid < 16) out[(size_t)t * DIM_V + vb + tid] = logit_l[tid] - lse;
    const float* hprev = (t & 1) ? hb1 : hb0;
    float*       hnext = (t & 1) ? hb0 : hb1;
    for (int i = tid; i < DIM_E; i += NTHR) ehbuf[i] = embed[(size_t)tok * DIM_E + i];
    for (int i = tid; i < DIM_H; i += NTHR) ehbuf[DIM_E + i] = hprev[i];
    float c_old = 0.f;
    if (tid < nH) c_old = cbg[h0 + tid];                  // prefetch (own slice)
    float encj = 0.f;
    if (t + 1 < T_FRAMES && wid < nH && lane == 0)
      encj = out[(size_t)(t + 1) * DIM_V + h0 + wid];     // prefetch enc_proj[t+1]
    __syncthreads();
    for (int c = wid; c < ncols; c += 4) {
      const float* wp = wxhl + c * 1152;
      float acc = 0.f;
      #pragma unroll
      for (int i = 0; i < 18; ++i) { int k = lane + (i << 6); acc += ehbuf[k] * wp[k]; }
      #pragma unroll
      for (int m = 32; m; m >>= 1) acc += __shfl_xor(acc, m);
      if (lane == 0) g_l[c] = acc + blst_l[c];
    }
    __syncthreads();
    if (tid < nH) {
      int gh = h0 + tid;
      float gi = g_l[tid * 4 + 0], gf = g_l[tid * 4 + 1];
      float gg = g_l[tid * 4 + 2], go_ = g_l[tid * 4 + 3];
      float c2 = sigm(gf) * c_old + sigm(gi) * tanhf(gg);
      float h2v = sigm(go_) * tanhf(c2);
      h2g[gh] = h2v;
      float h_old = ehbuf[DIM_E + gh];
      hnext[gh] = nb ? h2v : h_old;
      cbg[gh]   = nb ? c2 : c_old;
    }
    if (t == T_FRAMES - 1) break;
    gbar(barflag, bid, tid, bs); ++bs;

    // ---- phase 3: dp slice + commit dp + x for t+1 ----
    for (int i = tid; i < DIM_H; i += NTHR) h2l[i] = h2g[i];
    __syncthreads();
    if (wid < nH) {
      const float* wp = wdpl + wid * DIM_H;
      float acc = 0.f;
      #pragma unroll
      for (int i = 0; i < 10; ++i) { int k = lane + (i << 6); acc += h2l[k] * wp[k]; }
      #pragma unroll
      for (int m = 32; m; m >>= 1) acc += __shfl_xor(acc, m);
      if (lane == 0) {
        int gj = h0 + wid;
        float dp2 = acc + bdp_l[wid];
        float dpn = nb ? dp2 : dpcg[gj];
        dpcg[gj] = dpn;
        xg[gj] = tanhf(encj + dpn);
      }
    }
    gbar(barflag, bid, tid, bs); ++bs;
  }
}

extern "C" void kernel_launch(void* const* d_in, const int* in_sizes, int n_in,
                              void* d_out, int out_size, void* d_ws, size_t ws_size,
                              hipStream_t stream) {
  const float* enc    = (const float*)d_in[0];
  const float* embed  = (const float*)d_in[1];
  const float* Wx     = (const float*)d_in[2];
  const float* Wh     = (const float*)d_in[3];
  const float* b_lstm = (const float*)d_in[4];
  const float* Wdp    = (const float*)d_in[5];
  const float* bdp    = (const float*)d_in[6];
  const float* Wenc   = (const float*)d_in[7];
  const float* benc   = (const float*)d_in[8];
  const float* Wout   = (const float*)d_in[9];
  const float* bout   = (const float*)d_in[10];
  float* out = (float*)d_out;
  float* wsf = (float*)d_ws;
  unsigned* wsflags = (unsigned*)((char*)d_ws + (size_t)WF_END * 4);
  unsigned long long* wsgo =
      (unsigned long long*)((char*)d_ws + (size_t)WF_END * 4 + (size_t)FLG_CNT * 4);

  hipLaunchKernelGGL(rnnt_greedy_kernel, dim3(NBLK), dim3(NTHR), 0, stream,
                     enc, embed, Wx, Wh, b_lstm, Wdp, bdp, Wenc, benc, Wout, bout,
                     out, wsf, wsflags, wsgo);
}

// Round 3
// 114276.843 us; speedup vs baseline: 2.5828x; 2.5828x over previous
//
#include <hip/hip_runtime.h>
#include <stdint.h>

// ---------------- problem dims ----------------
#define T_FRAMES 8192
#define DIM_D 512
#define DIM_J 640
#define DIM_E 512
#define DIM_H 640
#define DIM_V 4096
#define G4H   2560
#define TOK_BLANK 4095
#define NBLK 256
#define NTHR 256

// ---------------- workspace layout (bytes) ----------------
// tagged 64-bit words: high32 = seq tag, low32 = payload bits
#define WS_HW   0                      // u64[640]  raw h2
#define WS_DW   (WS_HW + 640*8)        // u64[640]  raw dp2
#define WS_SA   (WS_DW + 640*8)        // u64[256]  block max
#define WS_SB   (WS_SA + 256*8)        // u64[256]  block sumexp
#define WS_SC   (WS_SB + 256*8)        // u64[256]  block argmax idx
#define WS_BAR  (WS_SC + 256*8)        // u32[256*16] init barrier flags

__device__ __forceinline__ float sigm(float x) { return 1.f / (1.f + __expf(-x)); }

__device__ __forceinline__ void st64(unsigned long long* p, unsigned tag, unsigned pay) {
  __hip_atomic_store(p, ((unsigned long long)tag << 32) | (unsigned long long)pay,
                     __ATOMIC_RELAXED, __HIP_MEMORY_SCOPE_AGENT);
}
__device__ __forceinline__ unsigned long long ld64(const unsigned long long* p) {
  return __hip_atomic_load(p, __ATOMIC_RELAXED, __HIP_MEMORY_SCOPE_AGENT);
}
// monotone tag check: poison 0xAAAAAAAA gives negative diff -> "not ready"
__device__ __forceinline__ bool tagok(unsigned long long w, unsigned tag) {
  return (int)((unsigned)(w >> 32) - tag) >= 0;
}

// classic release/acquire grid barrier -- used ONCE after init (enc_proj visibility)
__device__ __forceinline__ void gbar_init(unsigned* flags, int bid, int tid) {
  __syncthreads();
  if (tid == 0)
    __hip_atomic_store(&flags[bid * 16], 1u, __ATOMIC_RELEASE, __HIP_MEMORY_SCOPE_AGENT);
  unsigned f;
  do { f = __hip_atomic_load(&flags[tid * 16], __ATOMIC_RELAXED, __HIP_MEMORY_SCOPE_AGENT); }
  while ((int)(f - 1u) < 0);
  __builtin_amdgcn_fence(__ATOMIC_ACQUIRE, "agent");
  __syncthreads();
}

extern "C" __global__ void __launch_bounds__(NTHR, 1)
rnnt_greedy2(const float* __restrict__ enc,
             const float* __restrict__ embed,
             const float* __restrict__ Wx,
             const float* __restrict__ Wh,
             const float* __restrict__ b_lstm,
             const float* __restrict__ Wdp,
             const float* __restrict__ bdp,
             const float* __restrict__ Wenc,
             const float* __restrict__ benc,
             const float* __restrict__ Wout,
             const float* __restrict__ bout,
             float* __restrict__ out,
             unsigned long long* __restrict__ hw,
             unsigned long long* __restrict__ dw,
             unsigned long long* __restrict__ sA,
             unsigned long long* __restrict__ sB,
             unsigned long long* __restrict__ sC,
             unsigned* __restrict__ barflag)
{
  __shared__ float smem[29792];     // 119,168 B static LDS -> 1 block/CU

  const int tid  = threadIdx.x;
  const int bid  = blockIdx.x;
  const int wid  = tid >> 6;
  const int lane = tid & 63;

  float* woutl = smem;              // 16*640  Wout slice [vl][j]
  float* wxl   = smem + 10240;      // 12*512  Wx cols  [c][k]
  float* whl   = smem + 16384;      // 12*640  Wh cols  [c][k]
  float* wdpl  = smem + 24064;      // 3*640   Wdp cols [jl][k]
  float* h_com = smem + 25984;      // 640 committed h (replicated)
  float* h2_l  = smem + 26624;      // 640 raw h2 of current step
  float* dp_com= smem + 27264;      // 640 committed dp (replicated)
  float* x_l   = smem + 27904;      // 640 x = tanh(enc+dp)
  float* enc_l = smem + 28544;      // 640 enc_proj row t+1
  float* ebuf  = smem + 29184;      // 512 embed[tok]
  float* logit_l = smem + 29696;    // 16
  float* g_l     = smem + 29712;    // 12
  float* c_l     = smem + 29724;    // 4  owned c slice
  float* bout_l  = smem + 29728;    // 16
  float* blst_l  = smem + 29744;    // 12
  float* bdp_l   = smem + 29756;    // 4
  float* red     = smem + 29760;    // 32 reduce scratch
  float* enc_lds = smem;            // init overlay 32*512 = 16384 floats

  const int h0 = (bid * 5) >> 1;    // owned h == owned j slice
  const int h1 = ((bid + 1) * 5) >> 1;
  const int nH = h1 - h0;           // 2 or 3
  const int ncols = nH * 4;
  const int vb = bid << 4;          // 16 vocab entries per block

  // ================= init: enc_proj -> out[t][0:640] =================
  {
    const int r0 = bid * 32;
    const float4* src = (const float4*)(enc + (size_t)r0 * DIM_D);
    float4* dst = (float4*)enc_lds;
    for (int i = tid; i < 32 * DIM_D / 4; i += NTHR) dst[i] = src[i];
    __syncthreads();
    for (int jj = tid; jj < DIM_J; jj += NTHR) {
      float acc[32];
      #pragma unroll
      for (int r = 0; r < 32; ++r) acc[r] = 0.f;
      for (int k = 0; k < DIM_D; ++k) {
        float w = Wenc[(size_t)k * DIM_J + jj];
        #pragma unroll
        for (int r = 0; r < 32; ++r) acc[r] += enc_lds[r * DIM_D + k] * w;
      }
      float bj = benc[jj];
      for (int r = 0; r < 32; ++r) out[(size_t)(r0 + r) * DIM_V + jj] = acc[r] + bj;
    }
    __syncthreads();
  }

  // ================= init: weight slices -> LDS =================
  for (int idx = tid; idx < 16 * DIM_J; idx += NTHR) {
    int vl = idx / DIM_J, j = idx - vl * DIM_J;
    woutl[idx] = Wout[(size_t)j * DIM_V + vb + vl];
  }
  for (int idx = tid; idx < ncols * DIM_E; idx += NTHR) {
    int c = idx >> 9, k = idx & 511;
    int gcol = (c & 3) * DIM_H + h0 + (c >> 2);
    wxl[idx] = Wx[(size_t)k * G4H + gcol];
  }
  for (int idx = tid; idx < ncols * DIM_H; idx += NTHR) {
    int c = idx / DIM_H, k = idx - c * DIM_H;
    int gcol = (c & 3) * DIM_H + h0 + (c >> 2);
    whl[idx] = Wh[(size_t)k * G4H + gcol];
  }
  for (int idx = tid; idx < nH * DIM_H; idx += NTHR) {
    int jl = idx / DIM_H, k = idx - jl * DIM_H;
    wdpl[idx] = Wdp[(size_t)k * DIM_J + h0 + jl];
  }
  if (tid < 16) bout_l[tid] = bout[vb + tid];
  if (tid < ncols) blst_l[tid] = b_lstm[(tid & 3) * DIM_H + h0 + (tid >> 2)];
  if (tid < nH) bdp_l[tid] = bdp[h0 + tid];
  for (int i = tid; i < DIM_H; i += NTHR) h_com[i] = 0.f;
  if (tid < 4) c_l[tid] = 0.f;

  gbar_init(barflag, bid, tid);   // one-time: enc_proj + LDS ready everywhere

  // ================= main loop (t = -1 is the BLANK priming step) =================
  for (int t = -1; t < T_FRAMES; ++t) {
    const unsigned TAG = (unsigned)(t + 2);
    int tok; bool nb;

    if (t >= 0) {
      // ---- P1: logits slice from x_l ----
      {
        const float* w0 = woutl + (wid * 4 + 0) * DIM_J;
        const float* w1 = woutl + (wid * 4 + 1) * DIM_J;
        const float* w2 = woutl + (wid * 4 + 2) * DIM_J;
        const float* w3 = woutl + (wid * 4 + 3) * DIM_J;
        float a0 = 0, a1 = 0, a2 = 0, a3 = 0;
        #pragma unroll
        for (int i = 0; i < 10; ++i) {
          int k = lane + (i << 6);
          float xv = x_l[k];
          a0 += xv * w0[k]; a1 += xv * w1[k]; a2 += xv * w2[k]; a3 += xv * w3[k];
        }
        #pragma unroll
        for (int m = 32; m; m >>= 1) {
          a0 += __shfl_xor(a0, m); a1 += __shfl_xor(a1, m);
          a2 += __shfl_xor(a2, m); a3 += __shfl_xor(a3, m);
        }
        if (lane == 0) {
          logit_l[wid * 4 + 0] = a0 + bout_l[wid * 4 + 0];
          logit_l[wid * 4 + 1] = a1 + bout_l[wid * 4 + 1];
          logit_l[wid * 4 + 2] = a2 + bout_l[wid * 4 + 2];
          logit_l[wid * 4 + 3] = a3 + bout_l[wid * 4 + 3];
        }
      }
      __syncthreads();

      // prefetch enc_proj row t+1 (waves 1-3) while wave0 reduces block stats
      {
        int prow = (t + 1 < T_FRAMES) ? t + 1 : t;
        if (tid >= 64 && tid < 224) {
          float4 ef = *(const float4*)(out + (size_t)prow * DIM_V + (tid - 64) * 4);
          *(float4*)(enc_l + (tid - 64) * 4) = ef;
        }
      }
      if (wid == 0) {
        float v  = (lane < 16) ? logit_l[lane] : -3.4e38f;
        int   vi = vb + (lane & 15);
        float m = v; int mi = vi;
        #pragma unroll
        for (int s = 32; s; s >>= 1) {
          float om = __shfl_xor(m, s); int oi = __shfl_xor(mi, s);
          if (om > m || (om == m && oi < mi)) { m = om; mi = oi; }
        }
        float e = (lane < 16) ? __expf(v - m) : 0.f;
        #pragma unroll
        for (int s = 32; s; s >>= 1) e += __shfl_xor(e, s);
        if (lane == 0) {
          st64(sA + bid, TAG, __float_as_uint(m));
          st64(sB + bid, TAG, __float_as_uint(e));
          st64(sC + bid, TAG, (unsigned)mi);
        }
      }

      // ---- P1b: every block polls all 256 stats, combines locally ----
      unsigned long long wa = 0, wb = 0, wc = 0;
      {
        bool ra = false, rb = false, rc = false;
        while (!(ra && rb && rc)) {
          unsigned long long ta = wa, tb = wb, tc = wc;
          if (!ra) ta = ld64(sA + tid);
          if (!rb) tb = ld64(sB + tid);
          if (!rc) tc = ld64(sC + tid);
          if (!ra && tagok(ta, TAG)) { wa = ta; ra = true; }
          if (!rb && tagok(tb, TAG)) { wb = tb; rb = true; }
          if (!rc && tagok(tc, TAG)) { wc = tc; rc = true; }
          if (!(ra && rb && rc)) __builtin_amdgcn_s_sleep(1);
        }
      }
      const float mi0 = __uint_as_float((unsigned)wa);
      const float ei0 = __uint_as_float((unsigned)wb);
      const int   ii0 = (int)(unsigned)wc;
      // two-level argmax (ties -> lower index, blocks have disjoint ordered ranges)
      float m = mi0; int idx = ii0;
      #pragma unroll
      for (int s = 32; s; s >>= 1) {
        float om = __shfl_xor(m, s); int oi = __shfl_xor(idx, s);
        if (om > m || (om == m && oi < idx)) { m = om; idx = oi; }
      }
      if (lane == 0) { red[wid] = m; ((int*)red)[4 + wid] = idx; }
      __syncthreads();
      float gm = red[0]; int gtok = ((int*)red)[4];
      #pragma unroll
      for (int w = 1; w < 4; ++w) {
        float om = red[w]; int oi = ((int*)red)[4 + w];
        if (om > gm || (om == gm && oi < gtok)) { gm = om; gtok = oi; }
      }
      float term = ei0 * __expf(mi0 - gm);
      #pragma unroll
      for (int s = 32; s; s >>= 1) term += __shfl_xor(term, s);
      if (lane == 0) red[8 + wid] = term;
      __syncthreads();
      const float lse = gm + __logf(red[8] + red[9] + red[10] + red[11]);

      // logp write (off critical path)
      if (tid < 16) out[(size_t)t * DIM_V + vb + tid] = logit_l[tid] - lse;

      tok = gtok;
      nb = (tok != TOK_BLANK);
      if (t == T_FRAMES - 1) break;
    } else {
      // priming step: BLANK token, zero state, unconditional commit
      tok = TOK_BLANK;
      nb = true;
      if (tid >= 64 && tid < 224) {
        float4 ef = *(const float4*)(out + (size_t)(tid - 64) * 4);  // row 0
        *(float4*)(enc_l + (tid - 64) * 4) = ef;
      }
    }

    // ---- P2: LSTM gates for owned columns ----
    if (tid < 128) {
      float4 ev = *(const float4*)(embed + (size_t)tok * DIM_E + tid * 4);
      *(float4*)(ebuf + tid * 4) = ev;
    }
    __syncthreads();
    for (int c = wid; c < ncols; c += 4) {
      const float* wx = wxl + c * DIM_E;
      const float* wh = whl + c * DIM_H;
      float acc = 0.f;
      #pragma unroll
      for (int i = 0; i < 8; ++i)  { int k = lane + (i << 6); acc += ebuf[k] * wx[k]; }
      #pragma unroll
      for (int i = 0; i < 10; ++i) { int k = lane + (i << 6); acc += h_com[k] * wh[k]; }
      #pragma unroll
      for (int s = 32; s; s >>= 1) acc += __shfl_xor(acc, s);
      if (lane == 0) g_l[c] = acc + blst_l[c];
    }
    __syncthreads();
    if (tid < nH) {
      float c_old = c_l[tid];
      float gi = g_l[tid * 4 + 0], gf = g_l[tid * 4 + 1];
      float gg = g_l[tid * 4 + 2], go_ = g_l[tid * 4 + 3];
      float c2  = sigm(gf) * c_old + sigm(gi) * tanhf(gg);
      float h2v = sigm(go_) * tanhf(c2);
      c_l[tid] = nb ? c2 : c_old;
      st64(hw + h0 + tid, TAG, __float_as_uint(h2v));
    }

    // ---- P2b: poll all 640 raw h2 words; update replicated committed h ----
    {
      const bool has2 = (tid < 128);
      unsigned long long w0 = 0, w1 = 0, w2 = 0;
      bool r0 = false, r1 = false, r2 = !has2;
      while (!(r0 && r1 && r2)) {
        unsigned long long t0 = w0, t1 = w1, t2 = w2;
        if (!r0) t0 = ld64(hw + tid);
        if (!r1) t1 = ld64(hw + tid + 256);
        if (!r2) t2 = ld64(hw + tid + 512);
        if (!r0 && tagok(t0, TAG)) { w0 = t0; r0 = true; }
        if (!r1 && tagok(t1, TAG)) { w1 = t1; r1 = true; }
        if (!r2 && tagok(t2, TAG)) { w2 = t2; r2 = true; }
        if (!(r0 && r1 && r2)) __builtin_amdgcn_s_sleep(1);
      }
      float h2a = __uint_as_float((unsigned)w0);
      float h2b = __uint_as_float((unsigned)w1);
      h2_l[tid] = h2a;        h_com[tid]       = nb ? h2a : h_com[tid];
      h2_l[tid + 256] = h2b;  h_com[tid + 256] = nb ? h2b : h_com[tid + 256];
      if (has2) {
        float h2c = __uint_as_float((unsigned)w2);
        h2_l[tid + 512] = h2c; h_com[tid + 512] = nb ? h2c : h_com[tid + 512];
      }
    }
    __syncthreads();

    // ---- P3: dp for owned j columns (uses RAW h2) ----
    if (wid < nH) {
      const float* wp = wdpl + wid * DIM_H;
      float acc = 0.f;
      #pragma unroll
      for (int i = 0; i < 10; ++i) { int k = lane + (i << 6); acc += h2_l[k] * wp[k]; }
      #pragma unroll
      for (int s = 32; s; s >>= 1) acc += __shfl_xor(acc, s);
      if (lane == 0) st64(dw + h0 + wid, TAG, __float_as_uint(acc + bdp_l[wid]));
    }

    // ---- P3b: poll all 640 raw dp words; commit locally; build x for t+1 ----
    {
      const bool has2 = (tid < 128);
      unsigned long long w0 = 0, w1 = 0, w2 = 0;
      bool r0 = false, r1 = false, r2 = !has2;
      while (!(r0 && r1 && r2)) {
        unsigned long long t0 = w0, t1 = w1, t2 = w2;
        if (!r0) t0 = ld64(dw + tid);
        if (!r1) t1 = ld64(dw + tid + 256);
        if (!r2) t2 = ld64(dw + tid + 512);
        if (!r0 && tagok(t0, TAG)) { w0 = t0; r0 = true; }
        if (!r1 && tagok(t1, TAG)) { w1 = t1; r1 = true; }
        if (!r2 && tagok(t2, TAG)) { w2 = t2; r2 = true; }
        if (!(r0 && r1 && r2)) __builtin_amdgcn_s_sleep(1);
      }
      float d0 = __uint_as_float((unsigned)w0);
      float d1 = __uint_as_float((unsigned)w1);
      float dn0 = nb ? d0 : dp_com[tid];
      float dn1 = nb ? d1 : dp_com[tid + 256];
      dp_com[tid] = dn0;       x_l[tid]       = tanhf(enc_l[tid] + dn0);
      dp_com[tid + 256] = dn1; x_l[tid + 256] = tanhf(enc_l[tid + 256] + dn1);
      if (has2) {
        float d2 = __uint_as_float((unsigned)w2);
        float dn2 = nb ? d2 : dp_com[tid + 512];
        dp_com[tid + 512] = dn2; x_l[tid + 512] = tanhf(enc_l[tid + 512] + dn2);
      }
    }
    __syncthreads();
  }
}

extern "C" void kernel_launch(void* const* d_in, const int* in_sizes, int n_in,
                              void* d_out, int out_size, void* d_ws, size_t ws_size,
                              hipStream_t stream) {
  const float* enc    = (const float*)d_in[0];
  const float* embed  = (const float*)d_in[1];
  const float* Wx     = (const float*)d_in[2];
  const float* Wh     = (const float*)d_in[3];
  const float* b_lstm = (const float*)d_in[4];
  const float* Wdp    = (const float*)d_in[5];
  const float* bdp    = (const float*)d_in[6];
  const float* Wenc   = (const float*)d_in[7];
  const float* benc   = (const float*)d_in[8];
  const float* Wout   = (const float*)d_in[9];
  const float* bout   = (const float*)d_in[10];
  float* out = (float*)d_out;
  char* ws = (char*)d_ws;
  unsigned long long* hw = (unsigned long long*)(ws + WS_HW);
  unsigned long long* dw = (unsigned long long*)(ws + WS_DW);
  unsigned long long* sA = (unsigned long long*)(ws + WS_SA);
  unsigned long long* sB = (unsigned long long*)(ws + WS_SB);
  unsigned long long* sC = (unsigned long long*)(ws + WS_SC);
  unsigned* barflag = (unsigned*)(ws + WS_BAR);

  hipLaunchKernelGGL(rnnt_greedy2, dim3(NBLK), dim3(NTHR), 0, stream,
                     enc, embed, Wx, Wh, b_lstm, Wdp, bdp, Wenc, benc, Wout, bout,
                     out, hw, dw, sA, sB, sC, barflag);
}